// Round 8
// baseline (986.777 us; speedup 1.0000x reference)
//
#include <hip/hip_runtime.h>
#include <hip/hip_bf16.h>
#include <math.h>

// ---------------------------------------------------------------------------
// MambaBlock (bimamba v2). Round 7:
//  - all per-dir mid-section kernels batched over dir via gridDim.z
//    (conv / xproj / dtproj / aexp / scan_p1 / scan_mid / scan_p2)
//  - xproj reduce fused via atomicAdd (xdbl pre-zeroed)
//  - scan_mid writes h0 in-place into PQ[].x (H0 array eliminated)
//  - out_proj: 64x128 tile (384 blocks, was 192 at 6.5% occupancy)
//  - runtime layout select on ws_size: full dir-batched (~269MB) or
//    sequential-dir fallback (~167MB). Branch is ws_size-constant -> graph-safe.
// Shapes: B=4, L=1024, D_MODEL=768, D_INNER=1536, DT_RANK=48, D_STATE=16.
// ---------------------------------------------------------------------------

#define BB 4
#define LL 1024
#define DM 768
#define DI 1536
#define RK 48
#define NS 16
#define CH 32          // scan chunks
#define CLEN 32        // LL / CH
#define DB6 (DI / 256) // d-blocks per batch in scan
#define XKS 8          // x_proj split-K chunks
#define XKC 192        // 1536 / XKS

typedef __attribute__((ext_vector_type(8))) short bf16x8;
typedef __attribute__((ext_vector_type(4))) float f32x4;
typedef unsigned short us;

__device__ __forceinline__ float siluf(float x) {
    return x / (1.f + __expf(-x));
}
__device__ __forceinline__ float softplusf(float x) {
    return (x > 20.f) ? x : log1pf(__expf(x));
}
__device__ __forceinline__ us f2bf(float x) {
    __hip_bfloat16 h = __float2bfloat16(x);
    return *(us*)&h;
}
__device__ __forceinline__ void async_cp16(const void* g, void* l) {
    __builtin_amdgcn_global_load_lds(
        (const __attribute__((address_space(1))) void*)g,
        (__attribute__((address_space(3))) void*)l, 16, 0, 0);
}

// ---------------- zero fill (float4) ---------------------------------------
__global__ __launch_bounds__(256)
void zero_kernel(float4* __restrict__ p, int n4)
{
    int i = blockIdx.x * 256 + threadIdx.x;
    if (i < n4) p[i] = (float4){0.f, 0.f, 0.f, 0.f};
}

// ---------------- LayerNorm: one block per row of 768, bf16 out ------------
__global__ __launch_bounds__(256)
void ln_kernel(const float* __restrict__ h, const float* __restrict__ w,
               const float* __restrict__ bvec, us* __restrict__ out)
{
    int row = blockIdx.x;                 // 0 .. B*L-1
    const float* x = h + (size_t)row * DM;
    int tid = threadIdx.x;
    float v[3];
    float s = 0.f, s2 = 0.f;
#pragma unroll
    for (int j = 0; j < 3; ++j) {
        v[j] = x[tid + j * 256];
        s += v[j];
        s2 += v[j] * v[j];
    }
#pragma unroll
    for (int off = 32; off > 0; off >>= 1) {
        s += __shfl_down(s, off);
        s2 += __shfl_down(s2, off);
    }
    __shared__ float sw[4], sw2[4], stat[2];
    int wid = tid >> 6;
    if ((tid & 63) == 0) { sw[wid] = s; sw2[wid] = s2; }
    __syncthreads();
    if (tid == 0) {
        float a = sw[0] + sw[1] + sw[2] + sw[3];
        float a2 = sw2[0] + sw2[1] + sw2[2] + sw2[3];
        float mu = a * (1.f / DM);
        float var = a2 * (1.f / DM) - mu * mu;
        stat[0] = mu;
        stat[1] = rsqrtf(var + 1e-5f);
    }
    __syncthreads();
    float mu = stat[0], rs = stat[1];
    us* o = out + (size_t)row * DM;
#pragma unroll
    for (int j = 0; j < 3; ++j) {
        int i = tid + j * 256;
        o[i] = f2bf((v[j] - mu) * rs * w[i] + bvec[i]);
    }
}

// ---------------- fp32 -> bf16 cast (4 elems / thread) ---------------------
__global__ __launch_bounds__(256)
void cast_kernel(const float* __restrict__ x, us* __restrict__ y)
{
    int i = (blockIdx.x * 256 + threadIdx.x) * 4;
    float4 v = *(const float4*)(x + i);
    y[i + 0] = f2bf(v.x);
    y[i + 1] = f2bf(v.y);
    y[i + 2] = f2bf(v.z);
    y[i + 3] = f2bf(v.w);
}

// ---------------- Avm = -exp(A_log), dir-batched ---------------------------
__global__ __launch_bounds__(256)
void aexp_b(const float* __restrict__ a0, const float* __restrict__ a1,
            float* __restrict__ o0, float* __restrict__ o1)
{
    int z = blockIdx.z;
    const float* a = z ? a1 : a0;
    float* o = z ? o1 : o0;
    int i = blockIdx.x * 256 + threadIdx.x;     // over DI*NS
    o[i] = -expf(a[i]);
}

// ---------------- bf16 MFMA GEMM 128x128: C = A @ B^T (fp32) ---------------
__global__ __launch_bounds__(256)
void gemm_mfma_bt(const us* __restrict__ A, int lda,
                  const us* __restrict__ B, int ldb,
                  float* __restrict__ C, int ldc, int K)
{
    __shared__ us As[128 * 32];
    __shared__ us Bs[128 * 32];
    int tid = threadIdx.x;
    int wave = tid >> 6, lane = tid & 63;
    int wm = wave & 1, wn = wave >> 1;      // 2x2 wave grid
    int quad = lane >> 4, lr = lane & 15;
    int m0 = blockIdx.y * 128, n0 = blockIdx.x * 128;

    f32x4 acc[4][4];
#pragma unroll
    for (int i = 0; i < 4; ++i)
#pragma unroll
        for (int j = 0; j < 4; ++j) acc[i][j] = (f32x4){0.f, 0.f, 0.f, 0.f};

    for (int kt = 0; kt < K; kt += 32) {
#pragma unroll
        for (int i = 0; i < 2; ++i) {
            int idx = tid + i * 256;               // 0..511
            int row = idx >> 2, col = (idx & 3) * 8;
            async_cp16(A + (size_t)(m0 + row) * lda + kt + col, &As[idx * 8]);
            async_cp16(B + (size_t)(n0 + row) * ldb + kt + col, &Bs[idx * 8]);
        }
        __syncthreads();

        bf16x8 af[4], bf[4];
#pragma unroll
        for (int mt = 0; mt < 4; ++mt)
            af[mt] = *(const bf16x8*)(&As[(wm * 64 + mt * 16 + lr) * 32 + quad * 8]);
#pragma unroll
        for (int nt = 0; nt < 4; ++nt)
            bf[nt] = *(const bf16x8*)(&Bs[(wn * 64 + nt * 16 + lr) * 32 + quad * 8]);
#pragma unroll
        for (int mt = 0; mt < 4; ++mt)
#pragma unroll
            for (int nt = 0; nt < 4; ++nt)
                acc[mt][nt] = __builtin_amdgcn_mfma_f32_16x16x32_bf16(
                    af[mt], bf[nt], acc[mt][nt], 0, 0, 0);
        __syncthreads();
    }

#pragma unroll
    for (int mt = 0; mt < 4; ++mt)
#pragma unroll
        for (int nt = 0; nt < 4; ++nt)
#pragma unroll
            for (int e = 0; e < 4; ++e) {
                int m = m0 + wm * 64 + mt * 16 + quad * 4 + e;
                int n = n0 + wn * 64 + nt * 16 + lr;
                C[(size_t)m * ldc + n] = acc[mt][nt][e];
            }
}

// ---------------- bf16 MFMA GEMM 64x128 (for out_proj: more blocks) --------
__global__ __launch_bounds__(256)
void gemm_mfma_bt64(const us* __restrict__ A, int lda,
                    const us* __restrict__ B, int ldb,
                    float* __restrict__ C, int ldc, int K)
{
    __shared__ us As[64 * 32];
    __shared__ us Bs[128 * 32];
    int tid = threadIdx.x;
    int wave = tid >> 6, lane = tid & 63;
    int wm = wave & 1, wn = wave >> 1;      // wave: 32 rows x 64 cols
    int quad = lane >> 4, lr = lane & 15;
    int m0 = blockIdx.y * 64, n0 = blockIdx.x * 128;

    f32x4 acc[2][4];
#pragma unroll
    for (int i = 0; i < 2; ++i)
#pragma unroll
        for (int j = 0; j < 4; ++j) acc[i][j] = (f32x4){0.f, 0.f, 0.f, 0.f};

    for (int kt = 0; kt < K; kt += 32) {
        {   // A: 64x32 = 2048 elems = 256 x 16B
            int row = tid >> 2, col = (tid & 3) * 8;
            async_cp16(A + (size_t)(m0 + row) * lda + kt + col, &As[tid * 8]);
        }
#pragma unroll
        for (int i = 0; i < 2; ++i) {          // B: 128x32 = 512 x 16B
            int idx = tid + i * 256;
            int row = idx >> 2, col = (idx & 3) * 8;
            async_cp16(B + (size_t)(n0 + row) * ldb + kt + col, &Bs[idx * 8]);
        }
        __syncthreads();

        bf16x8 af[2], bf[4];
#pragma unroll
        for (int mt = 0; mt < 2; ++mt)
            af[mt] = *(const bf16x8*)(&As[(wm * 32 + mt * 16 + lr) * 32 + quad * 8]);
#pragma unroll
        for (int nt = 0; nt < 4; ++nt)
            bf[nt] = *(const bf16x8*)(&Bs[(wn * 64 + nt * 16 + lr) * 32 + quad * 8]);
#pragma unroll
        for (int mt = 0; mt < 2; ++mt)
#pragma unroll
            for (int nt = 0; nt < 4; ++nt)
                acc[mt][nt] = __builtin_amdgcn_mfma_f32_16x16x32_bf16(
                    af[mt], bf[nt], acc[mt][nt], 0, 0, 0);
        __syncthreads();
    }

#pragma unroll
    for (int mt = 0; mt < 2; ++mt)
#pragma unroll
        for (int nt = 0; nt < 4; ++nt)
#pragma unroll
            for (int e = 0; e < 4; ++e) {
                int m = m0 + wm * 32 + mt * 16 + quad * 4 + e;
                int n = n0 + wn * 64 + nt * 16 + lr;
                C[(size_t)m * ldc + n] = acc[mt][nt][e];
            }
}

// ---------------- causal depthwise conv (k=4) + silu, dir-batched ----------
__global__ __launch_bounds__(256)
void conv_b(const float* __restrict__ xz,
            const float* __restrict__ w0, const float* __restrict__ cb0,
            float* __restrict__ o0, int rev0,
            const float* __restrict__ w1, const float* __restrict__ cb1,
            float* __restrict__ o1, int rev1)
{
    int z = blockIdx.z;
    const float* w = z ? w1 : w0;
    const float* cb = z ? cb1 : cb0;
    float* xc = z ? o1 : o0;
    int rev = z ? rev1 : rev0;

    int gid = blockIdx.x * 256 + threadIdx.x;   // over B*L*DI
    int d = gid % DI;
    int bt = gid / DI;
    int t = bt % LL;
    int b = bt / LL;
    float acc = cb[d];
#pragma unroll
    for (int i = 0; i < 4; ++i) {
        int tt = t - 3 + i;
        if (tt >= 0) {
            int st = rev ? (LL - 1 - tt) : tt;
            acc += xz[((size_t)(b * LL + st)) * (2 * DI) + d] * w[d * 4 + i];
        }
    }
    xc[gid] = siluf(acc);
}

// ---------------- x_proj split-K GEMM, atomic reduce, dir-batched ----------
__global__ __launch_bounds__(256)
void xproj_b(const float* __restrict__ xc0, const float* __restrict__ xc1,
             const float* __restrict__ xw0, const float* __restrict__ xw1,
             float* __restrict__ xd0, float* __restrict__ xd1)
{
    int z = blockIdx.z;
    const float* A = z ? xc1 : xc0;
    const float* W = z ? xw1 : xw0;
    float* out = z ? xd1 : xd0;

    __shared__ float As[32][68];
    __shared__ float Ws[32][84];
    int tid = threadIdx.x;
    int tx = tid & 15, ty = tid >> 4;
    int k0 = blockIdx.x * XKC;
    int m0 = blockIdx.y * 64;

    float acc[4][5];
#pragma unroll
    for (int i = 0; i < 4; ++i)
#pragma unroll
        for (int j = 0; j < 5; ++j) acc[i][j] = 0.f;

    for (int kt = 0; kt < XKC; kt += 32) {
#pragma unroll
        for (int i = 0; i < 2; ++i) {
            int idx = tid + i * 256;
            int r = idx >> 3, c4 = (idx & 7) * 4;
            float4 v = *(const float4*)(A + (size_t)(m0 + r) * DI + k0 + kt + c4);
            As[c4 + 0][r] = v.x;
            As[c4 + 1][r] = v.y;
            As[c4 + 2][r] = v.z;
            As[c4 + 3][r] = v.w;
        }
        for (int idx = tid; idx < 640; idx += 256) {
            int r = idx >> 3, c4 = (idx & 7) * 4;
            float4 v = *(const float4*)(W + (size_t)r * DI + k0 + kt + c4);
            Ws[c4 + 0][r] = v.x;
            Ws[c4 + 1][r] = v.y;
            Ws[c4 + 2][r] = v.z;
            Ws[c4 + 3][r] = v.w;
        }
        __syncthreads();
#pragma unroll
        for (int kk = 0; kk < 32; ++kk) {
            float a[4], w[5];
#pragma unroll
            for (int i = 0; i < 4; ++i) a[i] = As[kk][ty * 4 + i];
#pragma unroll
            for (int j = 0; j < 5; ++j) w[j] = Ws[kk][tx + 16 * j];
#pragma unroll
            for (int i = 0; i < 4; ++i)
#pragma unroll
                for (int j = 0; j < 5; ++j) acc[i][j] += a[i] * w[j];
        }
        __syncthreads();
    }

#pragma unroll
    for (int i = 0; i < 4; ++i)
#pragma unroll
        for (int j = 0; j < 5; ++j)
            atomicAdd(&out[(size_t)(m0 + ty * 4 + i) * 80 + tx + 16 * j],
                      acc[i][j]);
}

// ---------------- dt_proj, dir-batched (R6 tile, VGPR-bounded) -------------
__global__ __launch_bounds__(256)
void dtproj_b(const float* __restrict__ xd0, const float* __restrict__ xd1,
              const float* __restrict__ W0, const float* __restrict__ W1,
              const float* __restrict__ b0, const float* __restrict__ b1,
              float* __restrict__ c0, float* __restrict__ c1)
{
    int z = blockIdx.z;
    const float* A = z ? xd1 : xd0;
    const float* W = z ? W1 : W0;
    const float* bias = z ? b1 : b0;
    float* C = z ? c1 : c0;

    __shared__ float As[32][48];    // [m][k]; reads broadcast
    __shared__ float Ws[48][128];   // [k][n]; b128 reads conflict-free
    int tid = threadIdx.x;
    int m0 = blockIdx.y * 32, n0 = blockIdx.x * 128;

    for (int i = tid; i < 384; i += 256) {
        int r = i / 12, j = i % 12;
        *(float4*)(&As[r][j * 4]) =
            *(const float4*)(A + (size_t)(m0 + r) * 80 + j * 4);
    }
    if (tid < 128) {
        const float* wr = W + (size_t)(n0 + tid) * RK;
#pragma unroll
        for (int j = 0; j < 12; ++j) {
            float4 v = *(const float4*)(wr + j * 4);
            Ws[j * 4 + 0][tid] = v.x;
            Ws[j * 4 + 1][tid] = v.y;
            Ws[j * 4 + 2][tid] = v.z;
            Ws[j * 4 + 3][tid] = v.w;
        }
    }
    __syncthreads();

    int tx = tid & 31, ty = tid >> 5;
    float acc[4][4];
#pragma unroll
    for (int i = 0; i < 4; ++i)
#pragma unroll
        for (int j = 0; j < 4; ++j) acc[i][j] = 0.f;

#pragma unroll 8
    for (int k = 0; k < RK; ++k) {
        float4 w = *(const float4*)(&Ws[k][tx * 4]);
        float a0 = As[ty * 4 + 0][k];
        float a1 = As[ty * 4 + 1][k];
        float a2 = As[ty * 4 + 2][k];
        float a3 = As[ty * 4 + 3][k];
        acc[0][0] += a0 * w.x; acc[0][1] += a0 * w.y;
        acc[0][2] += a0 * w.z; acc[0][3] += a0 * w.w;
        acc[1][0] += a1 * w.x; acc[1][1] += a1 * w.y;
        acc[1][2] += a1 * w.z; acc[1][3] += a1 * w.w;
        acc[2][0] += a2 * w.x; acc[2][1] += a2 * w.y;
        acc[2][2] += a2 * w.z; acc[2][3] += a2 * w.w;
        acc[3][0] += a3 * w.x; acc[3][1] += a3 * w.y;
        acc[3][2] += a3 * w.z; acc[3][3] += a3 * w.w;
    }

    float4 bv = *(const float4*)(bias + n0 + tx * 4);
#pragma unroll
    for (int i = 0; i < 4; ++i) {
        float4 o;
        o.x = softplusf(acc[i][0] + bv.x);
        o.y = softplusf(acc[i][1] + bv.y);
        o.z = softplusf(acc[i][2] + bv.z);
        o.w = softplusf(acc[i][3] + bv.w);
        *(float4*)(C + (size_t)(m0 + ty * 4 + i) * DI + n0 + tx * 4) = o;
    }
}

// ---------------- selective scan pass 1, dir-batched -----------------------
__global__ __launch_bounds__(256)
void scan_p1_b(const float* __restrict__ dt0, const float* __restrict__ dt1,
               const float* __restrict__ u0, const float* __restrict__ u1,
               const float* __restrict__ xd0, const float* __restrict__ xd1,
               const float* __restrict__ Av0, const float* __restrict__ Av1,
               float2* __restrict__ PQ0, float2* __restrict__ PQ1)
{
    int z = blockIdx.z;
    const float* dt = z ? dt1 : dt0;
    const float* u  = z ? u1 : u0;
    const float* xdbl = z ? xd1 : xd0;
    const float* Avm = z ? Av1 : Av0;
    float2* PQ = z ? PQ1 : PQ0;

    int c = blockIdx.y;
    int b = blockIdx.x / DB6;
    int d = (blockIdx.x % DB6) * 256 + threadIdx.x;

    float Av[16];
    {
        const float4* a4 = (const float4*)(Avm + (size_t)d * NS);
#pragma unroll
        for (int j = 0; j < 4; ++j) {
            float4 v = a4[j];
            Av[4 * j + 0] = v.x; Av[4 * j + 1] = v.y;
            Av[4 * j + 2] = v.z; Av[4 * j + 3] = v.w;
        }
    }

    __shared__ float Bs[CLEN * NS];
    for (int i = threadIdx.x; i < CLEN * NS; i += 256) {
        int t = i >> 4, n = i & 15;
        Bs[i] = xdbl[((size_t)(b * LL + c * CLEN + t)) * 80 + 48 + n];
    }
    __syncthreads();

    float q[16];
#pragma unroll
    for (int n = 0; n < 16; ++n) q[n] = 0.f;
    float dtsum = 0.f;

    size_t base = ((size_t)b * LL + c * CLEN) * DI + d;
    float dtr[8], ur[8];
#pragma unroll
    for (int i = 0; i < 8; ++i) {
        dtr[i] = dt[base + (size_t)i * DI];
        ur[i]  = u[base + (size_t)i * DI];
    }
#pragma unroll
    for (int t = 0; t < CLEN; ++t) {
        float dtv = dtr[t & 7], uv = ur[t & 7];
        if (t + 8 < CLEN) {
            dtr[t & 7] = dt[base + (size_t)(t + 8) * DI];
            ur[t & 7]  = u[base + (size_t)(t + 8) * DI];
        }
        float du = dtv * uv;
        dtsum += dtv;
        const float4* b4 = (const float4*)(Bs + t * NS);
#pragma unroll
        for (int j = 0; j < 4; ++j) {
            float4 Bv = b4[j];
            q[4 * j + 0] = __expf(dtv * Av[4 * j + 0]) * q[4 * j + 0] + du * Bv.x;
            q[4 * j + 1] = __expf(dtv * Av[4 * j + 1]) * q[4 * j + 1] + du * Bv.y;
            q[4 * j + 2] = __expf(dtv * Av[4 * j + 2]) * q[4 * j + 2] + du * Bv.z;
            q[4 * j + 3] = __expf(dtv * Av[4 * j + 3]) * q[4 * j + 3] + du * Bv.w;
        }
    }

    float2* o = PQ + (size_t)c * (BB * DI * NS) + (size_t)(b * DI + d) * NS;
#pragma unroll
    for (int n = 0; n < 16; ++n)
        o[n] = make_float2(__expf(dtsum * Av[n]), q[n]);
}

// ---------------- scan mid: prefix-compose; h0 written in-place to PQ.x ----
__global__ __launch_bounds__(256)
void scan_mid_b(float2* __restrict__ PQ0, float2* __restrict__ PQ1)
{
    int z = blockIdx.z;
    float2* PQ = z ? PQ1 : PQ0;
    int gid = blockIdx.x * 256 + threadIdx.x;   // over BB*DI*NS
    float h = 0.f;
#pragma unroll
    for (int c = 0; c < CH; ++c) {
        float2 s = PQ[(size_t)c * (BB * DI * NS) + gid];
        ((float*)&PQ[(size_t)c * (BB * DI * NS) + gid])[0] = h;  // h0 -> .x
        h = s.x * h + s.y;
    }
}

// ---------------- selective scan pass 2, dir-batched -----------------------
__global__ __launch_bounds__(256)
void scan_p2_b(const float* __restrict__ dt0, const float* __restrict__ dt1,
               const float* __restrict__ u0, const float* __restrict__ u1,
               const float* __restrict__ xd0, const float* __restrict__ xd1,
               const float* __restrict__ Av0, const float* __restrict__ Av1,
               const float* __restrict__ dp0, const float* __restrict__ dp1,
               const float2* __restrict__ PQ0, const float2* __restrict__ PQ1,
               float* __restrict__ g0, float* __restrict__ g1,
               int rev0, int rev1, int acc0, int acc1)
{
    int z = blockIdx.z;
    const float* dt = z ? dt1 : dt0;
    const float* u  = z ? u1 : u0;
    const float* xdbl = z ? xd1 : xd0;
    const float* Avm = z ? Av1 : Av0;
    const float* Dp = z ? dp1 : dp0;
    const float2* PQ = z ? PQ1 : PQ0;
    float* g = z ? g1 : g0;
    int rev = z ? rev1 : rev0;
    int accm = z ? acc1 : acc0;

    int c = blockIdx.y;
    int b = blockIdx.x / DB6;
    int d = (blockIdx.x % DB6) * 256 + threadIdx.x;

    float Av[16];
    {
        const float4* a4 = (const float4*)(Avm + (size_t)d * NS);
#pragma unroll
        for (int j = 0; j < 4; ++j) {
            float4 v = a4[j];
            Av[4 * j + 0] = v.x; Av[4 * j + 1] = v.y;
            Av[4 * j + 2] = v.z; Av[4 * j + 3] = v.w;
        }
    }
    float h[16];
    {
        const float2* h2 = PQ + (size_t)c * (BB * DI * NS)
                           + (size_t)(b * DI + d) * NS;
#pragma unroll
        for (int n = 0; n < 16; ++n) h[n] = h2[n].x;
    }
    float Dpv = Dp[d];

    __shared__ float Bs[CLEN * NS];
    __shared__ float Cs[CLEN * NS];
    for (int i = threadIdx.x; i < CLEN * NS; i += 256) {
        int t = i >> 4, n = i & 15;
        size_t src = ((size_t)(b * LL + c * CLEN + t)) * 80;
        Bs[i] = xdbl[src + 48 + n];
        Cs[i] = xdbl[src + 64 + n];
    }
    __syncthreads();

    size_t base = ((size_t)b * LL + c * CLEN) * DI + d;
    float dtr[8], ur[8];
#pragma unroll
    for (int i = 0; i < 8; ++i) {
        dtr[i] = dt[base + (size_t)i * DI];
        ur[i]  = u[base + (size_t)i * DI];
    }
#pragma unroll
    for (int t = 0; t < CLEN; ++t) {
        float dtv = dtr[t & 7], uv = ur[t & 7];
        if (t + 8 < CLEN) {
            dtr[t & 7] = dt[base + (size_t)(t + 8) * DI];
            ur[t & 7]  = u[base + (size_t)(t + 8) * DI];
        }
        float du = dtv * uv;
        float y = 0.f;
        const float4* b4 = (const float4*)(Bs + t * NS);
        const float4* c4 = (const float4*)(Cs + t * NS);
#pragma unroll
        for (int j = 0; j < 4; ++j) {
            float4 Bv = b4[j];
            float4 Cv = c4[j];
            h[4 * j + 0] = __expf(dtv * Av[4 * j + 0]) * h[4 * j + 0] + du * Bv.x;
            h[4 * j + 1] = __expf(dtv * Av[4 * j + 1]) * h[4 * j + 1] + du * Bv.y;
            h[4 * j + 2] = __expf(dtv * Av[4 * j + 2]) * h[4 * j + 2] + du * Bv.z;
            h[4 * j + 3] = __expf(dtv * Av[4 * j + 3]) * h[4 * j + 3] + du * Bv.w;
            y += h[4 * j + 0] * Cv.x + h[4 * j + 1] * Cv.y
               + h[4 * j + 2] * Cv.z + h[4 * j + 3] * Cv.w;
        }
        int tt = c * CLEN + t;
        int ot = rev ? (LL - 1 - tt) : tt;
        size_t oi = ((size_t)b * LL + ot) * DI + d;
        float val = y + uv * Dpv;
        if (accm) g[oi] += val;
        else      g[oi] = val;
    }
}

// ---------------- gate: gb = bf16((g0 [+ g1]) * silu(z)) -------------------
__global__ __launch_bounds__(256)
void gate2_kernel(const float* __restrict__ g0, const float* __restrict__ g1,
                  int dual, const float* __restrict__ xz, us* __restrict__ gb)
{
    int gid = blockIdx.x * 256 + threadIdx.x;   // over B*L*DI
    int d = gid % DI;
    int bt = gid / DI;
    float z = xz[(size_t)bt * (2 * DI) + DI + d];
    float gv = dual ? (g0[gid] + g1[gid]) : g0[gid];
    gb[gid] = f2bf(gv * siluf(z));
}

// ---------------------------------------------------------------------------
extern "C" void kernel_launch(void* const* d_in, const int* in_sizes, int n_in,
                              void* d_out, int out_size, void* d_ws, size_t ws_size,
                              hipStream_t stream)
{
    const float* h_r        = (const float*)d_in[0];
    const float* h_i        = (const float*)d_in[1];
    const float* ln_w       = (const float*)d_in[2];
    const float* ln_b       = (const float*)d_in[3];
    const float* in_w       = (const float*)d_in[4];
    const float* conv_w     = (const float*)d_in[5];
    const float* conv_bias  = (const float*)d_in[6];
    const float* xp_w       = (const float*)d_in[7];
    const float* dtp_w      = (const float*)d_in[8];
    const float* dtp_bias   = (const float*)d_in[9];
    const float* A_log      = (const float*)d_in[10];
    const float* D_p        = (const float*)d_in[11];
    const float* conv_w_b   = (const float*)d_in[12];
    const float* conv_bias_b= (const float*)d_in[13];
    const float* xp_w_b     = (const float*)d_in[14];
    const float* dtp_w_b    = (const float*)d_in[15];
    const float* dtp_bias_b = (const float*)d_in[16];
    const float* A_b_log    = (const float*)d_in[17];
    const float* D_b        = (const float*)d_in[18];
    const float* out_w      = (const float*)d_in[19];
    float* out = (float*)d_out;

    const size_t E = (size_t)BB * LL * DI;      // 6,291,456
    const size_t XD = (size_t)BB * LL * 80;     // 327,680
    const size_t AV = (size_t)DI * NS;          // 24,576
    const size_t PQN = (size_t)CH * BB * DI * NS; // 3,145,728 float2

    // full (dir-batched) layout needs:
    const size_t needF = (8 * E + 2 * XD + 2 * AV + 4 * PQN) * 4
                       + ((size_t)2 * 2 * DI * DM + (size_t)2 * DM * DI) * 2;
    const bool full = ws_size >= needF;

    float* p = (float*)d_ws;
    float* g0 = p; p += E;
    float* g1 = full ? p : g0; if (full) p += E;
    float* xz = p; p += 2 * E;
    float* xc0 = p; p += E;
    float* xc1 = full ? p : xc0; if (full) p += E;
    float* dtb0 = p; p += E;
    float* dtb1 = full ? p : dtb0; if (full) p += E;
    float* xd0 = p; p += XD;
    float* xd1 = full ? p : xd0; if (full) p += XD;
    float* Av0 = p; p += AV;
    float* Av1 = full ? p : Av0; if (full) p += AV;
    float2* PQ0 = (float2*)p; p += 2 * PQN;
    float2* PQ1 = full ? (float2*)p : PQ0; if (full) p += 2 * PQN;
    us* wbi = (us*)p;                           // both branches: 4,718,592 us
    us* wbo = wbi + (size_t)2 * 2 * DI * DM;    // both branches: 2,359,296 us
    us* gb  = (us*)PQ0;   // alias: live gate->out_proj, PQ dead by then
    us* hnb = (us*)xc0;   // alias: live ln->in_proj, xc written after

    const size_t out_stride = (size_t)BB * LL * DM;

    // cast all weights once (both branches)
    cast_kernel<<<(2 * 2 * DI * DM) / 1024, 256, 0, stream>>>(in_w, wbi);
    cast_kernel<<<(2 * DM * DI) / 1024, 256, 0, stream>>>(out_w, wbo);

    for (int br = 0; br < 2; ++br) {
        const float* h = br ? h_i : h_r;
        const us* wbi_b = wbi + (size_t)br * 2 * DI * DM;
        const us* wbo_b = wbo + (size_t)br * DM * DI;
        const float* cw_f = conv_w + (size_t)br * DI * 4;
        const float* cb_f = conv_bias + (size_t)br * DI;
        const float* xw_f = xp_w + (size_t)br * 80 * DI;
        const float* dw_f = dtp_w + (size_t)br * DI * RK;
        const float* db_f = dtp_bias + (size_t)br * DI;
        const float* al_f = A_log + (size_t)br * DI * NS;
        const float* dp_f = D_p + (size_t)br * DI;
        const float* cw_b = conv_w_b + (size_t)br * DI * 4;
        const float* cb_b = conv_bias_b + (size_t)br * DI;
        const float* xw_b = xp_w_b + (size_t)br * 80 * DI;
        const float* dw_b = dtp_w_b + (size_t)br * DI * RK;
        const float* db_b = dtp_bias_b + (size_t)br * DI;
        const float* al_b = A_b_log + (size_t)br * DI * NS;
        const float* dp_b = D_b + (size_t)br * DI;

        ln_kernel<<<BB * LL, 256, 0, stream>>>(h, ln_w + br * DM, ln_b + br * DM, hnb);

        // xz = hn @ in_w.T   [4096 x 3072], K=768  (bf16 MFMA, 768 blocks)
        gemm_mfma_bt<<<dim3((2 * DI) / 128, (BB * LL) / 128), 256, 0, stream>>>(
            hnb, DM, wbi_b, DM, xz, 2 * DI, DM);

        if (full) {
            conv_b<<<dim3((int)(E / 256), 1, 2), 256, 0, stream>>>(
                xz, cw_f, cb_f, xc0, 0, cw_b, cb_b, xc1, 1);
            zero_kernel<<<(int)(2 * XD / 4 + 255) / 256, 256, 0, stream>>>(
                (float4*)xd0, (int)(2 * XD / 4));
            xproj_b<<<dim3(XKS, (BB * LL) / 64, 2), 256, 0, stream>>>(
                xc0, xc1, xw_f, xw_b, xd0, xd1);
            dtproj_b<<<dim3(DI / 128, (BB * LL) / 32, 2), 256, 0, stream>>>(
                xd0, xd1, dw_f, dw_b, db_f, db_b, dtb0, dtb1);
            aexp_b<<<dim3((int)(AV / 256), 1, 2), 256, 0, stream>>>(
                al_f, al_b, Av0, Av1);
            scan_p1_b<<<dim3(BB * DB6, CH, 2), 256, 0, stream>>>(
                dtb0, dtb1, xc0, xc1, xd0, xd1, Av0, Av1, PQ0, PQ1);
            scan_mid_b<<<dim3((int)((BB * DI * NS) / 256), 1, 2), 256, 0, stream>>>(
                PQ0, PQ1);
            scan_p2_b<<<dim3(BB * DB6, CH, 2), 256, 0, stream>>>(
                dtb0, dtb1, xc0, xc1, xd0, xd1, Av0, Av1, dp_f, dp_b,
                PQ0, PQ1, g0, g1, 0, 1, 0, 0);
            gate2_kernel<<<(int)(E / 256), 256, 0, stream>>>(g0, g1, 1, xz, gb);
        } else {
            for (int dir = 0; dir < 2; ++dir) {
                const float* cw = dir ? cw_b : cw_f;
                const float* cb = dir ? cb_b : cb_f;
                const float* xw = dir ? xw_b : xw_f;
                const float* dw = dir ? dw_b : dw_f;
                const float* db = dir ? db_b : db_f;
                const float* al = dir ? al_b : al_f;
                const float* dp = dir ? dp_b : dp_f;

                conv_b<<<dim3((int)(E / 256), 1, 1), 256, 0, stream>>>(
                    xz, cw, cb, xc0, dir, cw, cb, xc0, dir);
                zero_kernel<<<(int)(XD / 4 + 255) / 256, 256, 0, stream>>>(
                    (float4*)xd0, (int)(XD / 4));
                xproj_b<<<dim3(XKS, (BB * LL) / 64, 1), 256, 0, stream>>>(
                    xc0, xc0, xw, xw, xd0, xd0);
                dtproj_b<<<dim3(DI / 128, (BB * LL) / 32, 1), 256, 0, stream>>>(
                    xd0, xd0, dw, dw, db, db, dtb0, dtb0);
                aexp_b<<<dim3((int)(AV / 256), 1, 1), 256, 0, stream>>>(
                    al, al, Av0, Av0);
                scan_p1_b<<<dim3(BB * DB6, CH, 1), 256, 0, stream>>>(
                    dtb0, dtb0, xc0, xc0, xd0, xd0, Av0, Av0, PQ0, PQ0);
                scan_mid_b<<<dim3((int)((BB * DI * NS) / 256), 1, 1), 256, 0, stream>>>(
                    PQ0, PQ0);
                scan_p2_b<<<dim3(BB * DB6, CH, 1), 256, 0, stream>>>(
                    dtb0, dtb0, xc0, xc0, xd0, xd0, Av0, Av0, dp, dp,
                    PQ0, PQ0, g0, g0, dir, dir, dir, dir);
            }
            gate2_kernel<<<(int)(E / 256), 256, 0, stream>>>(g0, g0, 0, xz, gb);
        }

        // out = g @ out_w.T   [4096 x 768], K=1536  (bf16 MFMA, 64x128 tile)
        gemm_mfma_bt64<<<dim3(DM / 128, (BB * LL) / 64), 256, 0, stream>>>(
            gb, DI, wbo_b, DI, out + br * out_stride, DM, DI);
    }
}

// Round 9
// 890.302 us; speedup vs baseline: 1.1084x; 1.1084x over previous
//
#include <hip/hip_runtime.h>
#include <hip/hip_bf16.h>
#include <math.h>

// ---------------------------------------------------------------------------
// MambaBlock (bimamba v2). Round 8:
//  - R7's dir-batched path never ran: needF exceeded ws_size (256 MiB) by
//    196 KB -> silent fallback. Fixed by (a) fusing -exp(A_log) into the scan
//    kernels (Av arrays deleted), (b) per-branch weight cast buffers.
//    needF now 261.4 MB < 268.4 MB -> full mode active.
// Shapes: B=4, L=1024, D_MODEL=768, D_INNER=1536, DT_RANK=48, D_STATE=16.
// ---------------------------------------------------------------------------

#define BB 4
#define LL 1024
#define DM 768
#define DI 1536
#define RK 48
#define NS 16
#define CH 32          // scan chunks
#define CLEN 32        // LL / CH
#define DB6 (DI / 256) // d-blocks per batch in scan
#define XKS 8          // x_proj split-K chunks
#define XKC 192        // 1536 / XKS

typedef __attribute__((ext_vector_type(8))) short bf16x8;
typedef __attribute__((ext_vector_type(4))) float f32x4;
typedef unsigned short us;

__device__ __forceinline__ float siluf(float x) {
    return x / (1.f + __expf(-x));
}
__device__ __forceinline__ float softplusf(float x) {
    return (x > 20.f) ? x : log1pf(__expf(x));
}
__device__ __forceinline__ us f2bf(float x) {
    __hip_bfloat16 h = __float2bfloat16(x);
    return *(us*)&h;
}
__device__ __forceinline__ void async_cp16(const void* g, void* l) {
    __builtin_amdgcn_global_load_lds(
        (const __attribute__((address_space(1))) void*)g,
        (__attribute__((address_space(3))) void*)l, 16, 0, 0);
}

// ---------------- zero fill (float4) ---------------------------------------
__global__ __launch_bounds__(256)
void zero_kernel(float4* __restrict__ p, int n4)
{
    int i = blockIdx.x * 256 + threadIdx.x;
    if (i < n4) p[i] = (float4){0.f, 0.f, 0.f, 0.f};
}

// ---------------- LayerNorm: one block per row of 768, bf16 out ------------
__global__ __launch_bounds__(256)
void ln_kernel(const float* __restrict__ h, const float* __restrict__ w,
               const float* __restrict__ bvec, us* __restrict__ out)
{
    int row = blockIdx.x;                 // 0 .. B*L-1
    const float* x = h + (size_t)row * DM;
    int tid = threadIdx.x;
    float v[3];
    float s = 0.f, s2 = 0.f;
#pragma unroll
    for (int j = 0; j < 3; ++j) {
        v[j] = x[tid + j * 256];
        s += v[j];
        s2 += v[j] * v[j];
    }
#pragma unroll
    for (int off = 32; off > 0; off >>= 1) {
        s += __shfl_down(s, off);
        s2 += __shfl_down(s2, off);
    }
    __shared__ float sw[4], sw2[4], stat[2];
    int wid = tid >> 6;
    if ((tid & 63) == 0) { sw[wid] = s; sw2[wid] = s2; }
    __syncthreads();
    if (tid == 0) {
        float a = sw[0] + sw[1] + sw[2] + sw[3];
        float a2 = sw2[0] + sw2[1] + sw2[2] + sw2[3];
        float mu = a * (1.f / DM);
        float var = a2 * (1.f / DM) - mu * mu;
        stat[0] = mu;
        stat[1] = rsqrtf(var + 1e-5f);
    }
    __syncthreads();
    float mu = stat[0], rs = stat[1];
    us* o = out + (size_t)row * DM;
#pragma unroll
    for (int j = 0; j < 3; ++j) {
        int i = tid + j * 256;
        o[i] = f2bf((v[j] - mu) * rs * w[i] + bvec[i]);
    }
}

// ---------------- fp32 -> bf16 cast (4 elems / thread) ---------------------
__global__ __launch_bounds__(256)
void cast_kernel(const float* __restrict__ x, us* __restrict__ y)
{
    int i = (blockIdx.x * 256 + threadIdx.x) * 4;
    float4 v = *(const float4*)(x + i);
    y[i + 0] = f2bf(v.x);
    y[i + 1] = f2bf(v.y);
    y[i + 2] = f2bf(v.z);
    y[i + 3] = f2bf(v.w);
}

// ---------------- bf16 MFMA GEMM 128x128: C = A @ B^T (fp32) ---------------
__global__ __launch_bounds__(256)
void gemm_mfma_bt(const us* __restrict__ A, int lda,
                  const us* __restrict__ B, int ldb,
                  float* __restrict__ C, int ldc, int K)
{
    __shared__ us As[128 * 32];
    __shared__ us Bs[128 * 32];
    int tid = threadIdx.x;
    int wave = tid >> 6, lane = tid & 63;
    int wm = wave & 1, wn = wave >> 1;      // 2x2 wave grid
    int quad = lane >> 4, lr = lane & 15;
    int m0 = blockIdx.y * 128, n0 = blockIdx.x * 128;

    f32x4 acc[4][4];
#pragma unroll
    for (int i = 0; i < 4; ++i)
#pragma unroll
        for (int j = 0; j < 4; ++j) acc[i][j] = (f32x4){0.f, 0.f, 0.f, 0.f};

    for (int kt = 0; kt < K; kt += 32) {
#pragma unroll
        for (int i = 0; i < 2; ++i) {
            int idx = tid + i * 256;               // 0..511
            int row = idx >> 2, col = (idx & 3) * 8;
            async_cp16(A + (size_t)(m0 + row) * lda + kt + col, &As[idx * 8]);
            async_cp16(B + (size_t)(n0 + row) * ldb + kt + col, &Bs[idx * 8]);
        }
        __syncthreads();

        bf16x8 af[4], bf[4];
#pragma unroll
        for (int mt = 0; mt < 4; ++mt)
            af[mt] = *(const bf16x8*)(&As[(wm * 64 + mt * 16 + lr) * 32 + quad * 8]);
#pragma unroll
        for (int nt = 0; nt < 4; ++nt)
            bf[nt] = *(const bf16x8*)(&Bs[(wn * 64 + nt * 16 + lr) * 32 + quad * 8]);
#pragma unroll
        for (int mt = 0; mt < 4; ++mt)
#pragma unroll
            for (int nt = 0; nt < 4; ++nt)
                acc[mt][nt] = __builtin_amdgcn_mfma_f32_16x16x32_bf16(
                    af[mt], bf[nt], acc[mt][nt], 0, 0, 0);
        __syncthreads();
    }

#pragma unroll
    for (int mt = 0; mt < 4; ++mt)
#pragma unroll
        for (int nt = 0; nt < 4; ++nt)
#pragma unroll
            for (int e = 0; e < 4; ++e) {
                int m = m0 + wm * 64 + mt * 16 + quad * 4 + e;
                int n = n0 + wn * 64 + nt * 16 + lr;
                C[(size_t)m * ldc + n] = acc[mt][nt][e];
            }
}

// ---------------- bf16 MFMA GEMM 64x128 (for out_proj: more blocks) --------
__global__ __launch_bounds__(256)
void gemm_mfma_bt64(const us* __restrict__ A, int lda,
                    const us* __restrict__ B, int ldb,
                    float* __restrict__ C, int ldc, int K)
{
    __shared__ us As[64 * 32];
    __shared__ us Bs[128 * 32];
    int tid = threadIdx.x;
    int wave = tid >> 6, lane = tid & 63;
    int wm = wave & 1, wn = wave >> 1;      // wave: 32 rows x 64 cols
    int quad = lane >> 4, lr = lane & 15;
    int m0 = blockIdx.y * 64, n0 = blockIdx.x * 128;

    f32x4 acc[2][4];
#pragma unroll
    for (int i = 0; i < 2; ++i)
#pragma unroll
        for (int j = 0; j < 4; ++j) acc[i][j] = (f32x4){0.f, 0.f, 0.f, 0.f};

    for (int kt = 0; kt < K; kt += 32) {
        {   // A: 64x32 = 2048 elems = 256 x 16B
            int row = tid >> 2, col = (tid & 3) * 8;
            async_cp16(A + (size_t)(m0 + row) * lda + kt + col, &As[tid * 8]);
        }
#pragma unroll
        for (int i = 0; i < 2; ++i) {          // B: 128x32 = 512 x 16B
            int idx = tid + i * 256;
            int row = idx >> 2, col = (idx & 3) * 8;
            async_cp16(B + (size_t)(n0 + row) * ldb + kt + col, &Bs[idx * 8]);
        }
        __syncthreads();

        bf16x8 af[2], bf[4];
#pragma unroll
        for (int mt = 0; mt < 2; ++mt)
            af[mt] = *(const bf16x8*)(&As[(wm * 32 + mt * 16 + lr) * 32 + quad * 8]);
#pragma unroll
        for (int nt = 0; nt < 4; ++nt)
            bf[nt] = *(const bf16x8*)(&Bs[(wn * 64 + nt * 16 + lr) * 32 + quad * 8]);
#pragma unroll
        for (int mt = 0; mt < 2; ++mt)
#pragma unroll
            for (int nt = 0; nt < 4; ++nt)
                acc[mt][nt] = __builtin_amdgcn_mfma_f32_16x16x32_bf16(
                    af[mt], bf[nt], acc[mt][nt], 0, 0, 0);
        __syncthreads();
    }

#pragma unroll
    for (int mt = 0; mt < 2; ++mt)
#pragma unroll
        for (int nt = 0; nt < 4; ++nt)
#pragma unroll
            for (int e = 0; e < 4; ++e) {
                int m = m0 + wm * 32 + mt * 16 + quad * 4 + e;
                int n = n0 + wn * 64 + nt * 16 + lr;
                C[(size_t)m * ldc + n] = acc[mt][nt][e];
            }
}

// ---------------- causal depthwise conv (k=4) + silu, dir-batched ----------
__global__ __launch_bounds__(256)
void conv_b(const float* __restrict__ xz,
            const float* __restrict__ w0, const float* __restrict__ cb0,
            float* __restrict__ o0, int rev0,
            const float* __restrict__ w1, const float* __restrict__ cb1,
            float* __restrict__ o1, int rev1)
{
    int z = blockIdx.z;
    const float* w = z ? w1 : w0;
    const float* cb = z ? cb1 : cb0;
    float* xc = z ? o1 : o0;
    int rev = z ? rev1 : rev0;

    int gid = blockIdx.x * 256 + threadIdx.x;   // over B*L*DI
    int d = gid % DI;
    int bt = gid / DI;
    int t = bt % LL;
    int b = bt / LL;
    float acc = cb[d];
#pragma unroll
    for (int i = 0; i < 4; ++i) {
        int tt = t - 3 + i;
        if (tt >= 0) {
            int st = rev ? (LL - 1 - tt) : tt;
            acc += xz[((size_t)(b * LL + st)) * (2 * DI) + d] * w[d * 4 + i];
        }
    }
    xc[gid] = siluf(acc);
}

// ---------------- x_proj split-K GEMM, atomic reduce, dir-batched ----------
__global__ __launch_bounds__(256)
void xproj_b(const float* __restrict__ xc0, const float* __restrict__ xc1,
             const float* __restrict__ xw0, const float* __restrict__ xw1,
             float* __restrict__ xd0, float* __restrict__ xd1)
{
    int z = blockIdx.z;
    const float* A = z ? xc1 : xc0;
    const float* W = z ? xw1 : xw0;
    float* out = z ? xd1 : xd0;

    __shared__ float As[32][68];
    __shared__ float Ws[32][84];
    int tid = threadIdx.x;
    int tx = tid & 15, ty = tid >> 4;
    int k0 = blockIdx.x * XKC;
    int m0 = blockIdx.y * 64;

    float acc[4][5];
#pragma unroll
    for (int i = 0; i < 4; ++i)
#pragma unroll
        for (int j = 0; j < 5; ++j) acc[i][j] = 0.f;

    for (int kt = 0; kt < XKC; kt += 32) {
#pragma unroll
        for (int i = 0; i < 2; ++i) {
            int idx = tid + i * 256;
            int r = idx >> 3, c4 = (idx & 7) * 4;
            float4 v = *(const float4*)(A + (size_t)(m0 + r) * DI + k0 + kt + c4);
            As[c4 + 0][r] = v.x;
            As[c4 + 1][r] = v.y;
            As[c4 + 2][r] = v.z;
            As[c4 + 3][r] = v.w;
        }
        for (int idx = tid; idx < 640; idx += 256) {
            int r = idx >> 3, c4 = (idx & 7) * 4;
            float4 v = *(const float4*)(W + (size_t)r * DI + k0 + kt + c4);
            Ws[c4 + 0][r] = v.x;
            Ws[c4 + 1][r] = v.y;
            Ws[c4 + 2][r] = v.z;
            Ws[c4 + 3][r] = v.w;
        }
        __syncthreads();
#pragma unroll
        for (int kk = 0; kk < 32; ++kk) {
            float a[4], w[5];
#pragma unroll
            for (int i = 0; i < 4; ++i) a[i] = As[kk][ty * 4 + i];
#pragma unroll
            for (int j = 0; j < 5; ++j) w[j] = Ws[kk][tx + 16 * j];
#pragma unroll
            for (int i = 0; i < 4; ++i)
#pragma unroll
                for (int j = 0; j < 5; ++j) acc[i][j] += a[i] * w[j];
        }
        __syncthreads();
    }

#pragma unroll
    for (int i = 0; i < 4; ++i)
#pragma unroll
        for (int j = 0; j < 5; ++j)
            atomicAdd(&out[(size_t)(m0 + ty * 4 + i) * 80 + tx + 16 * j],
                      acc[i][j]);
}

// ---------------- dt_proj, dir-batched (VGPR-bounded) ----------------------
__global__ __launch_bounds__(256)
void dtproj_b(const float* __restrict__ xd0, const float* __restrict__ xd1,
              const float* __restrict__ W0, const float* __restrict__ W1,
              const float* __restrict__ b0, const float* __restrict__ b1,
              float* __restrict__ c0, float* __restrict__ c1)
{
    int z = blockIdx.z;
    const float* A = z ? xd1 : xd0;
    const float* W = z ? W1 : W0;
    const float* bias = z ? b1 : b0;
    float* C = z ? c1 : c0;

    __shared__ float As[32][48];    // [m][k]; reads broadcast
    __shared__ float Ws[48][128];   // [k][n]; b128 reads conflict-free
    int tid = threadIdx.x;
    int m0 = blockIdx.y * 32, n0 = blockIdx.x * 128;

    for (int i = tid; i < 384; i += 256) {
        int r = i / 12, j = i % 12;
        *(float4*)(&As[r][j * 4]) =
            *(const float4*)(A + (size_t)(m0 + r) * 80 + j * 4);
    }
    if (tid < 128) {
        const float* wr = W + (size_t)(n0 + tid) * RK;
#pragma unroll
        for (int j = 0; j < 12; ++j) {
            float4 v = *(const float4*)(wr + j * 4);
            Ws[j * 4 + 0][tid] = v.x;
            Ws[j * 4 + 1][tid] = v.y;
            Ws[j * 4 + 2][tid] = v.z;
            Ws[j * 4 + 3][tid] = v.w;
        }
    }
    __syncthreads();

    int tx = tid & 31, ty = tid >> 5;
    float acc[4][4];
#pragma unroll
    for (int i = 0; i < 4; ++i)
#pragma unroll
        for (int j = 0; j < 4; ++j) acc[i][j] = 0.f;

#pragma unroll 8
    for (int k = 0; k < RK; ++k) {
        float4 w = *(const float4*)(&Ws[k][tx * 4]);
        float a0 = As[ty * 4 + 0][k];
        float a1 = As[ty * 4 + 1][k];
        float a2 = As[ty * 4 + 2][k];
        float a3 = As[ty * 4 + 3][k];
        acc[0][0] += a0 * w.x; acc[0][1] += a0 * w.y;
        acc[0][2] += a0 * w.z; acc[0][3] += a0 * w.w;
        acc[1][0] += a1 * w.x; acc[1][1] += a1 * w.y;
        acc[1][2] += a1 * w.z; acc[1][3] += a1 * w.w;
        acc[2][0] += a2 * w.x; acc[2][1] += a2 * w.y;
        acc[2][2] += a2 * w.z; acc[2][3] += a2 * w.w;
        acc[3][0] += a3 * w.x; acc[3][1] += a3 * w.y;
        acc[3][2] += a3 * w.z; acc[3][3] += a3 * w.w;
    }

    float4 bv = *(const float4*)(bias + n0 + tx * 4);
#pragma unroll
    for (int i = 0; i < 4; ++i) {
        float4 o;
        o.x = softplusf(acc[i][0] + bv.x);
        o.y = softplusf(acc[i][1] + bv.y);
        o.z = softplusf(acc[i][2] + bv.z);
        o.w = softplusf(acc[i][3] + bv.w);
        *(float4*)(C + (size_t)(m0 + ty * 4 + i) * DI + n0 + tx * 4) = o;
    }
}

// ---------------- selective scan pass 1, dir-batched, Av fused -------------
__global__ __launch_bounds__(256)
void scan_p1_b(const float* __restrict__ dt0, const float* __restrict__ dt1,
               const float* __restrict__ u0, const float* __restrict__ u1,
               const float* __restrict__ xd0, const float* __restrict__ xd1,
               const float* __restrict__ al0, const float* __restrict__ al1,
               float2* __restrict__ PQ0, float2* __restrict__ PQ1)
{
    int z = blockIdx.z;
    const float* dt = z ? dt1 : dt0;
    const float* u  = z ? u1 : u0;
    const float* xdbl = z ? xd1 : xd0;
    const float* Alog = z ? al1 : al0;
    float2* PQ = z ? PQ1 : PQ0;

    int c = blockIdx.y;
    int b = blockIdx.x / DB6;
    int d = (blockIdx.x % DB6) * 256 + threadIdx.x;

    float Av[16];
    {
        const float4* a4 = (const float4*)(Alog + (size_t)d * NS);
#pragma unroll
        for (int j = 0; j < 4; ++j) {
            float4 v = a4[j];
            Av[4 * j + 0] = -expf(v.x); Av[4 * j + 1] = -expf(v.y);
            Av[4 * j + 2] = -expf(v.z); Av[4 * j + 3] = -expf(v.w);
        }
    }

    __shared__ float Bs[CLEN * NS];
    for (int i = threadIdx.x; i < CLEN * NS; i += 256) {
        int t = i >> 4, n = i & 15;
        Bs[i] = xdbl[((size_t)(b * LL + c * CLEN + t)) * 80 + 48 + n];
    }
    __syncthreads();

    float q[16];
#pragma unroll
    for (int n = 0; n < 16; ++n) q[n] = 0.f;
    float dtsum = 0.f;

    size_t base = ((size_t)b * LL + c * CLEN) * DI + d;
    float dtr[8], ur[8];
#pragma unroll
    for (int i = 0; i < 8; ++i) {
        dtr[i] = dt[base + (size_t)i * DI];
        ur[i]  = u[base + (size_t)i * DI];
    }
#pragma unroll
    for (int t = 0; t < CLEN; ++t) {
        float dtv = dtr[t & 7], uv = ur[t & 7];
        if (t + 8 < CLEN) {
            dtr[t & 7] = dt[base + (size_t)(t + 8) * DI];
            ur[t & 7]  = u[base + (size_t)(t + 8) * DI];
        }
        float du = dtv * uv;
        dtsum += dtv;
        const float4* b4 = (const float4*)(Bs + t * NS);
#pragma unroll
        for (int j = 0; j < 4; ++j) {
            float4 Bv = b4[j];
            q[4 * j + 0] = __expf(dtv * Av[4 * j + 0]) * q[4 * j + 0] + du * Bv.x;
            q[4 * j + 1] = __expf(dtv * Av[4 * j + 1]) * q[4 * j + 1] + du * Bv.y;
            q[4 * j + 2] = __expf(dtv * Av[4 * j + 2]) * q[4 * j + 2] + du * Bv.z;
            q[4 * j + 3] = __expf(dtv * Av[4 * j + 3]) * q[4 * j + 3] + du * Bv.w;
        }
    }

    float2* o = PQ + (size_t)c * (BB * DI * NS) + (size_t)(b * DI + d) * NS;
#pragma unroll
    for (int n = 0; n < 16; ++n)
        o[n] = make_float2(__expf(dtsum * Av[n]), q[n]);
}

// ---------------- scan mid: prefix-compose; h0 written in-place to PQ.x ----
__global__ __launch_bounds__(256)
void scan_mid_b(float2* __restrict__ PQ0, float2* __restrict__ PQ1)
{
    int z = blockIdx.z;
    float2* PQ = z ? PQ1 : PQ0;
    int gid = blockIdx.x * 256 + threadIdx.x;   // over BB*DI*NS
    float h = 0.f;
#pragma unroll
    for (int c = 0; c < CH; ++c) {
        float2 s = PQ[(size_t)c * (BB * DI * NS) + gid];
        ((float*)&PQ[(size_t)c * (BB * DI * NS) + gid])[0] = h;  // h0 -> .x
        h = s.x * h + s.y;
    }
}

// ---------------- selective scan pass 2, dir-batched, Av fused -------------
__global__ __launch_bounds__(256)
void scan_p2_b(const float* __restrict__ dt0, const float* __restrict__ dt1,
               const float* __restrict__ u0, const float* __restrict__ u1,
               const float* __restrict__ xd0, const float* __restrict__ xd1,
               const float* __restrict__ al0, const float* __restrict__ al1,
               const float* __restrict__ dp0, const float* __restrict__ dp1,
               const float2* __restrict__ PQ0, const float2* __restrict__ PQ1,
               float* __restrict__ g0, float* __restrict__ g1,
               int rev0, int rev1, int acc0, int acc1)
{
    int z = blockIdx.z;
    const float* dt = z ? dt1 : dt0;
    const float* u  = z ? u1 : u0;
    const float* xdbl = z ? xd1 : xd0;
    const float* Alog = z ? al1 : al0;
    const float* Dp = z ? dp1 : dp0;
    const float2* PQ = z ? PQ1 : PQ0;
    float* g = z ? g1 : g0;
    int rev = z ? rev1 : rev0;
    int accm = z ? acc1 : acc0;

    int c = blockIdx.y;
    int b = blockIdx.x / DB6;
    int d = (blockIdx.x % DB6) * 256 + threadIdx.x;

    float Av[16];
    {
        const float4* a4 = (const float4*)(Alog + (size_t)d * NS);
#pragma unroll
        for (int j = 0; j < 4; ++j) {
            float4 v = a4[j];
            Av[4 * j + 0] = -expf(v.x); Av[4 * j + 1] = -expf(v.y);
            Av[4 * j + 2] = -expf(v.z); Av[4 * j + 3] = -expf(v.w);
        }
    }
    float h[16];
    {
        const float2* h2 = PQ + (size_t)c * (BB * DI * NS)
                           + (size_t)(b * DI + d) * NS;
#pragma unroll
        for (int n = 0; n < 16; ++n) h[n] = h2[n].x;
    }
    float Dpv = Dp[d];

    __shared__ float Bs[CLEN * NS];
    __shared__ float Cs[CLEN * NS];
    for (int i = threadIdx.x; i < CLEN * NS; i += 256) {
        int t = i >> 4, n = i & 15;
        size_t src = ((size_t)(b * LL + c * CLEN + t)) * 80;
        Bs[i] = xdbl[src + 48 + n];
        Cs[i] = xdbl[src + 64 + n];
    }
    __syncthreads();

    size_t base = ((size_t)b * LL + c * CLEN) * DI + d;
    float dtr[8], ur[8];
#pragma unroll
    for (int i = 0; i < 8; ++i) {
        dtr[i] = dt[base + (size_t)i * DI];
        ur[i]  = u[base + (size_t)i * DI];
    }
#pragma unroll
    for (int t = 0; t < CLEN; ++t) {
        float dtv = dtr[t & 7], uv = ur[t & 7];
        if (t + 8 < CLEN) {
            dtr[t & 7] = dt[base + (size_t)(t + 8) * DI];
            ur[t & 7]  = u[base + (size_t)(t + 8) * DI];
        }
        float du = dtv * uv;
        float y = 0.f;
        const float4* b4 = (const float4*)(Bs + t * NS);
        const float4* c4 = (const float4*)(Cs + t * NS);
#pragma unroll
        for (int j = 0; j < 4; ++j) {
            float4 Bv = b4[j];
            float4 Cv = c4[j];
            h[4 * j + 0] = __expf(dtv * Av[4 * j + 0]) * h[4 * j + 0] + du * Bv.x;
            h[4 * j + 1] = __expf(dtv * Av[4 * j + 1]) * h[4 * j + 1] + du * Bv.y;
            h[4 * j + 2] = __expf(dtv * Av[4 * j + 2]) * h[4 * j + 2] + du * Bv.z;
            h[4 * j + 3] = __expf(dtv * Av[4 * j + 3]) * h[4 * j + 3] + du * Bv.w;
            y += h[4 * j + 0] * Cv.x + h[4 * j + 1] * Cv.y
               + h[4 * j + 2] * Cv.z + h[4 * j + 3] * Cv.w;
        }
        int tt = c * CLEN + t;
        int ot = rev ? (LL - 1 - tt) : tt;
        size_t oi = ((size_t)b * LL + ot) * DI + d;
        float val = y + uv * Dpv;
        if (accm) g[oi] += val;
        else      g[oi] = val;
    }
}

// ---------------- gate: gb = bf16((g0 [+ g1]) * silu(z)) -------------------
__global__ __launch_bounds__(256)
void gate2_kernel(const float* __restrict__ g0, const float* __restrict__ g1,
                  int dual, const float* __restrict__ xz, us* __restrict__ gb)
{
    int gid = blockIdx.x * 256 + threadIdx.x;   // over B*L*DI
    int d = gid % DI;
    int bt = gid / DI;
    float z = xz[(size_t)bt * (2 * DI) + DI + d];
    float gv = dual ? (g0[gid] + g1[gid]) : g0[gid];
    gb[gid] = f2bf(gv * siluf(z));
}

// ---------------------------------------------------------------------------
extern "C" void kernel_launch(void* const* d_in, const int* in_sizes, int n_in,
                              void* d_out, int out_size, void* d_ws, size_t ws_size,
                              hipStream_t stream)
{
    const float* h_r        = (const float*)d_in[0];
    const float* h_i        = (const float*)d_in[1];
    const float* ln_w       = (const float*)d_in[2];
    const float* ln_b       = (const float*)d_in[3];
    const float* in_w       = (const float*)d_in[4];
    const float* conv_w     = (const float*)d_in[5];
    const float* conv_bias  = (const float*)d_in[6];
    const float* xp_w       = (const float*)d_in[7];
    const float* dtp_w      = (const float*)d_in[8];
    const float* dtp_bias   = (const float*)d_in[9];
    const float* A_log      = (const float*)d_in[10];
    const float* D_p        = (const float*)d_in[11];
    const float* conv_w_b   = (const float*)d_in[12];
    const float* conv_bias_b= (const float*)d_in[13];
    const float* xp_w_b     = (const float*)d_in[14];
    const float* dtp_w_b    = (const float*)d_in[15];
    const float* dtp_bias_b = (const float*)d_in[16];
    const float* A_b_log    = (const float*)d_in[17];
    const float* D_b        = (const float*)d_in[18];
    const float* out_w      = (const float*)d_in[19];
    float* out = (float*)d_out;

    const size_t E = (size_t)BB * LL * DI;        // 6,291,456
    const size_t XD = (size_t)BB * LL * 80;       // 327,680
    const size_t PQN = (size_t)CH * BB * DI * NS; // 3,145,728 float2 elems

    // full (dir-batched) layout: 8E + 2XD + 4PQN floats + per-branch weights
    const size_t needF = (8 * E + 2 * XD + 4 * PQN) * 4
                       + ((size_t)2 * DI * DM + (size_t)DM * DI) * 2;
    const bool full = ws_size >= needF;

    float* p = (float*)d_ws;
    float* g0 = p; p += E;
    float* g1 = full ? p : g0; if (full) p += E;
    float* xz = p; p += 2 * E;
    float* xc0 = p; p += E;
    float* xc1 = full ? p : xc0; if (full) p += E;
    float* dtb0 = p; p += E;
    float* dtb1 = full ? p : dtb0; if (full) p += E;
    float* xd0 = p; p += XD;
    float* xd1 = full ? p : xd0; if (full) p += XD;
    float2* PQ0 = (float2*)p; p += 2 * PQN;
    float2* PQ1 = full ? (float2*)p : PQ0; if (full) p += 2 * PQN;
    us* wbi_b = (us*)p;                          // per-branch: 2,359,296 us
    us* wbo_b = wbi_b + (size_t)2 * DI * DM;     // per-branch: 1,179,648 us
    us* gb  = (us*)PQ0;   // alias: live gate->out_proj, PQ dead by then
    us* hnb = (us*)xc0;   // alias: live ln->in_proj, xc written after

    const size_t out_stride = (size_t)BB * LL * DM;

    for (int br = 0; br < 2; ++br) {
        const float* h = br ? h_i : h_r;
        const float* cw_f = conv_w + (size_t)br * DI * 4;
        const float* cb_f = conv_bias + (size_t)br * DI;
        const float* xw_f = xp_w + (size_t)br * 80 * DI;
        const float* dw_f = dtp_w + (size_t)br * DI * RK;
        const float* db_f = dtp_bias + (size_t)br * DI;
        const float* al_f = A_log + (size_t)br * DI * NS;
        const float* dp_f = D_p + (size_t)br * DI;
        const float* cw_b = conv_w_b + (size_t)br * DI * 4;
        const float* cb_b = conv_bias_b + (size_t)br * DI;
        const float* xw_b = xp_w_b + (size_t)br * 80 * DI;
        const float* dw_b = dtp_w_b + (size_t)br * DI * RK;
        const float* db_b = dtp_bias_b + (size_t)br * DI;
        const float* al_b = A_b_log + (size_t)br * DI * NS;
        const float* dp_b = D_b + (size_t)br * DI;

        // cast this branch's weights to bf16
        cast_kernel<<<(2 * DI * DM) / 1024, 256, 0, stream>>>(
            in_w + (size_t)br * 2 * DI * DM, wbi_b);
        cast_kernel<<<(DM * DI) / 1024, 256, 0, stream>>>(
            out_w + (size_t)br * DM * DI, wbo_b);

        ln_kernel<<<BB * LL, 256, 0, stream>>>(h, ln_w + br * DM, ln_b + br * DM, hnb);

        // xz = hn @ in_w.T   [4096 x 3072], K=768  (bf16 MFMA, 768 blocks)
        gemm_mfma_bt<<<dim3((2 * DI) / 128, (BB * LL) / 128), 256, 0, stream>>>(
            hnb, DM, wbi_b, DM, xz, 2 * DI, DM);

        if (full) {
            conv_b<<<dim3((int)(E / 256), 1, 2), 256, 0, stream>>>(
                xz, cw_f, cb_f, xc0, 0, cw_b, cb_b, xc1, 1);
            zero_kernel<<<(int)(2 * XD / 4 + 255) / 256, 256, 0, stream>>>(
                (float4*)xd0, (int)(2 * XD / 4));
            xproj_b<<<dim3(XKS, (BB * LL) / 64, 2), 256, 0, stream>>>(
                xc0, xc1, xw_f, xw_b, xd0, xd1);
            dtproj_b<<<dim3(DI / 128, (BB * LL) / 32, 2), 256, 0, stream>>>(
                xd0, xd1, dw_f, dw_b, db_f, db_b, dtb0, dtb1);
            scan_p1_b<<<dim3(BB * DB6, CH, 2), 256, 0, stream>>>(
                dtb0, dtb1, xc0, xc1, xd0, xd1, al_f, al_b, PQ0, PQ1);
            scan_mid_b<<<dim3((int)((BB * DI * NS) / 256), 1, 2), 256, 0, stream>>>(
                PQ0, PQ1);
            scan_p2_b<<<dim3(BB * DB6, CH, 2), 256, 0, stream>>>(
                dtb0, dtb1, xc0, xc1, xd0, xd1, al_f, al_b, dp_f, dp_b,
                PQ0, PQ1, g0, g1, 0, 1, 0, 0);
            gate2_kernel<<<(int)(E / 256), 256, 0, stream>>>(g0, g1, 1, xz, gb);
        } else {
            for (int dir = 0; dir < 2; ++dir) {
                const float* cw = dir ? cw_b : cw_f;
                const float* cb = dir ? cb_b : cb_f;
                const float* xw = dir ? xw_b : xw_f;
                const float* dw = dir ? dw_b : dw_f;
                const float* db = dir ? db_b : db_f;
                const float* al = dir ? al_b : al_f;
                const float* dp = dir ? dp_b : dp_f;

                conv_b<<<dim3((int)(E / 256), 1, 1), 256, 0, stream>>>(
                    xz, cw, cb, xc0, dir, cw, cb, xc0, dir);
                zero_kernel<<<(int)(XD / 4 + 255) / 256, 256, 0, stream>>>(
                    (float4*)xd0, (int)(XD / 4));
                xproj_b<<<dim3(XKS, (BB * LL) / 64, 1), 256, 0, stream>>>(
                    xc0, xc0, xw, xw, xd0, xd0);
                dtproj_b<<<dim3(DI / 128, (BB * LL) / 32, 1), 256, 0, stream>>>(
                    xd0, xd0, dw, dw, db, db, dtb0, dtb0);
                scan_p1_b<<<dim3(BB * DB6, CH, 1), 256, 0, stream>>>(
                    dtb0, dtb0, xc0, xc0, xd0, xd0, al, al, PQ0, PQ0);
                scan_mid_b<<<dim3((int)((BB * DI * NS) / 256), 1, 1), 256, 0, stream>>>(
                    PQ0, PQ0);
                scan_p2_b<<<dim3(BB * DB6, CH, 1), 256, 0, stream>>>(
                    dtb0, dtb0, xc0, xc0, xd0, xd0, al, al, dp, dp,
                    PQ0, PQ0, g0, g0, dir, dir, dir, dir);
            }
            gate2_kernel<<<(int)(E / 256), 256, 0, stream>>>(g0, g0, 0, xz, gb);
        }

        // out = g @ out_w.T   [4096 x 768], K=1536  (bf16 MFMA, 64x128 tile)
        gemm_mfma_bt64<<<dim3(DM / 128, (BB * LL) / 64), 256, 0, stream>>>(
            gb, DI, wbo_b, DI, out + br * out_stride, DM, DI);
    }
}